// Round 16
// baseline (283.340 us; speedup 1.0000x reference)
//
#include <hip/hip_runtime.h>

#define D_MODEL 1024
#define D_STATE 16
#define D_INNER 2048
#define DT_RANK 64
#define NBATCH 2
#define SEQ_L 1024
#define M_ROWS (NBATCH * SEQ_L)   // 2048
#define CHUNK 32
#define NCHUNK (SEQ_L / CHUNK)    // 32

typedef __bf16 bf16x8 __attribute__((ext_vector_type(8)));
typedef float f32x4 __attribute__((ext_vector_type(4)));
typedef unsigned short u16;
typedef unsigned int u32;
typedef u16 u16x8 __attribute__((ext_vector_type(8)));

__device__ __forceinline__ float bf2f(u16 h) {
    return __uint_as_float(((unsigned)h) << 16);
}
__device__ __forceinline__ u16 f2bf(float f) {
    unsigned u = __float_as_uint(f);
    u += 0x7fff + ((u >> 16) & 1);   // round-to-nearest-even
    return (u16)(u >> 16);
}

// ---------------- prep: scalar weight casts + xd zero + LayerNorm ----------------
// blocks [0,25856): casts; [25856,26048): zero xd; rest: LN rows
__global__ __launch_bounds__(256) void prep(
    const float* __restrict__ s0, const float* __restrict__ s1,
    const float* __restrict__ s2, const float* __restrict__ s3,
    u16* __restrict__ d0, u16* __restrict__ d1,
    u16* __restrict__ d2, u16* __restrict__ d3,
    const float* __restrict__ x, const float* __restrict__ g,
    const float* __restrict__ b, u16* __restrict__ xn,
    float* __restrict__ xd) {
    int blk = blockIdx.x;
    if (blk < 25856) {
        int idx = blk * 256 + threadIdx.x;
        if (idx < 4194304) {
            d0[idx] = f2bf(s0[idx]);
        } else if (idx < 6291456) {
            int i = idx - 4194304; d1[i] = f2bf(s1[i]);
        } else if (idx < 6488064) {
            int i = idx - 6291456; d2[i] = f2bf(s2[i]);
        } else {
            int i = idx - 6488064; d3[i] = f2bf(s3[i]);
        }
        return;
    }
    if (blk < 26048) {
        int zi = (blk - 25856) * 256 + threadIdx.x;   // float4 index < 49152
        ((float4*)xd)[zi] = (float4){0.f, 0.f, 0.f, 0.f};
        return;
    }
    int row = blk - 26048;
    const float4* xr = (const float4*)(x + (size_t)row * D_MODEL);
    float4 v = xr[threadIdx.x];
    float s  = v.x + v.y + v.z + v.w;
    float ss = v.x * v.x + v.y * v.y + v.z * v.z + v.w * v.w;
#pragma unroll
    for (int off = 32; off > 0; off >>= 1) {
        s  += __shfl_down(s,  off, 64);
        ss += __shfl_down(ss, off, 64);
    }
    __shared__ float sh_s[4], sh_ss[4];
    int wid = threadIdx.x >> 6;
    if ((threadIdx.x & 63) == 0) { sh_s[wid] = s; sh_ss[wid] = ss; }
    __syncthreads();
    float mu  = (sh_s[0] + sh_s[1] + sh_s[2] + sh_s[3]) * (1.0f / D_MODEL);
    float var = (sh_ss[0] + sh_ss[1] + sh_ss[2] + sh_ss[3]) * (1.0f / D_MODEL) - mu * mu;
    float rs = rsqrtf(var + 1e-5f);
    int c0 = threadIdx.x * 4;
    float vv[4] = {v.x, v.y, v.z, v.w};
#pragma unroll
    for (int j = 0; j < 4; j++) {
        int c = c0 + j;
        float o = (vv[j] - mu) * rs * g[c] + b[c];
        xn[(size_t)row * D_MODEL + c] = f2bf(o);
    }
}

// ============ LDS-staged B^T GEMM — 2-phase double-buffered pipeline (kept, ~neutral+) ============
// MODE 0: bf16 store. MODE 4: f32 partial store to outF + z*M_ROWS*ldC.
template <int BM, int BN, int WM, int WN, int MODE>
__global__ __launch_bounds__(256) void gemm_lds(
    const __bf16* __restrict__ A, const __bf16* __restrict__ W,
    int K, int Ksteps, int ldC,
    float* __restrict__ outF, u16* __restrict__ outB) {
    constexpr int WCOLS = BN / (WN * 16);
    __shared__ __bf16 As[2][BM * 32];
    __shared__ __bf16 Bs[2][BN * 32];
    int tid  = threadIdx.x;
    int lane = tid & 63;
    int wid  = tid >> 6;
    int l16  = lane & 15;
    int quad = lane >> 4;
    int wr = wid / WCOLS;
    int wc = wid % WCOLS;
    int m0 = blockIdx.y * BM;
    int n0 = blockIdx.x * BN;
    int kbase = blockIdx.z * Ksteps * 32;

    f32x4 acc[WM][WN];
#pragma unroll
    for (int mi = 0; mi < WM; mi++)
#pragma unroll
        for (int nj = 0; nj < WN; nj++)
            acc[mi][nj] = (f32x4){0.f, 0.f, 0.f, 0.f};

    auto STAGE = [&](int buf, int ki) {
        int k0 = kbase + ki * 32;
#pragma unroll
        for (int i = 0; i < BM / 64; i++) {
            int t   = i * 256 + tid;
            int row = t >> 2;
            int cg  = (t & 3) ^ ((row >> 1) & 3);
            __builtin_amdgcn_global_load_lds(
                (const __attribute__((address_space(1))) u32*)(A + (size_t)(m0 + row) * K + k0 + cg * 8),
                (__attribute__((address_space(3))) u32*)(As[buf] + (i * 256 + wid * 64) * 8),
                16, 0, 0);
        }
#pragma unroll
        for (int i = 0; i < BN / 64; i++) {
            int t   = i * 256 + tid;
            int row = t >> 2;
            int cg  = (t & 3) ^ ((row >> 1) & 3);
            __builtin_amdgcn_global_load_lds(
                (const __attribute__((address_space(1))) u32*)(W + (size_t)(n0 + row) * K + k0 + cg * 8),
                (__attribute__((address_space(3))) u32*)(Bs[buf] + (i * 256 + wid * 64) * 8),
                16, 0, 0);
        }
    };

    STAGE(0, 0);
    __syncthreads();   // prologue: buf0 ready

    int cur = 0;
    for (int ki = 0; ki < Ksteps; ki++) {
        if (ki + 1 < Ksteps) STAGE(cur ^ 1, ki + 1);   // prefetch flies under compute

        bf16x8 af[WM], bfr[WN];
#pragma unroll
        for (int mi = 0; mi < WM; mi++) {
            int r  = wr * WM * 16 + mi * 16 + l16;
            int cg = quad ^ ((r >> 1) & 3);
            af[mi] = *(const bf16x8*)(As[cur] + r * 32 + cg * 8);
        }
#pragma unroll
        for (int nj = 0; nj < WN; nj++) {
            int r  = wc * WN * 16 + nj * 16 + l16;
            int cg = quad ^ ((r >> 1) & 3);
            bfr[nj] = *(const bf16x8*)(Bs[cur] + r * 32 + cg * 8);
        }
#pragma unroll
        for (int mi = 0; mi < WM; mi++)
#pragma unroll
            for (int nj = 0; nj < WN; nj++)
                acc[mi][nj] = __builtin_amdgcn_mfma_f32_16x16x32_bf16(
                    af[mi], bfr[nj], acc[mi][nj], 0, 0, 0);

        __syncthreads();   // drains prefetch (vmcnt0) + all waves done reading cur
        cur ^= 1;
    }

    float* outP = (MODE == 4) ? outF + (size_t)blockIdx.z * M_ROWS * ldC : outF;
#pragma unroll
    for (int mi = 0; mi < WM; mi++) {
#pragma unroll
        for (int nj = 0; nj < WN; nj++) {
            int col = n0 + wc * WN * 16 + nj * 16 + l16;
#pragma unroll
            for (int r = 0; r < 4; r++) {
                int row = m0 + wr * WM * 16 + mi * 16 + quad * 4 + r;
                float v = acc[mi][nj][r];
                if (MODE == 0) {
                    outB[(size_t)row * ldC + col] = f2bf(v);
                } else {
                    outP[(size_t)row * ldC + col] = v;
                }
            }
        }
    }
}

// ---------------- out_proj partial reduce (4 partials) + residual ----------------
__global__ __launch_bounds__(256) void out_reduce(
    const float* __restrict__ p, const float* __restrict__ x,
    float* __restrict__ out) {
    int idx = blockIdx.x * 256 + threadIdx.x;   // float4 index
    const int N = M_ROWS * D_MODEL;
    float4 a = ((const float4*)p)[idx];
    float4 b = ((const float4*)(p + N))[idx];
    float4 c = ((const float4*)(p + 2 * N))[idx];
    float4 d = ((const float4*)(p + 3 * N))[idx];
    float4 r = ((const float4*)x)[idx];
    float4 o;
    o.x = a.x + b.x + c.x + d.x + r.x;
    o.y = a.y + b.y + c.y + d.y + r.y;
    o.z = a.z + b.z + c.z + d.z + r.z;
    o.w = a.w + b.w + c.w + d.w + r.w;
    ((float4*)out)[idx] = o;
}

// ---------------- x_proj GEMM: K-split partials accumulated via f32 atomicAdd ----------------
// xd pre-zeroed in prep (0.75 MB, L2-resident). grid (2, 32, 8).
__global__ __launch_bounds__(256) void gemm_xp(
    const __bf16* __restrict__ A, const __bf16* __restrict__ W,
    float* __restrict__ outF) {
    const int K = D_INNER, Ksplit = D_INNER / 8, Nw = 96;
    int lane = threadIdx.x & 63;
    int wid  = threadIdx.x >> 6;
    int m0 = blockIdx.y * 64;
    int n0 = blockIdx.x * 64;
    int kc = blockIdx.z;
    int l16  = lane & 15;
    int quad = lane >> 4;
    int mrow = m0 + wid * 16 + l16;

    const __bf16* ap = A + (size_t)mrow * K + kc * Ksplit + quad * 8;
    const __bf16* wp[4];
#pragma unroll
    for (int j = 0; j < 4; j++) {
        int nc = n0 + j * 16 + l16;
        if (nc > Nw - 1) nc = Nw - 1;
        wp[j] = W + (size_t)nc * K + kc * Ksplit + quad * 8;
    }
    f32x4 acc[4];
#pragma unroll
    for (int j = 0; j < 4; j++) acc[j] = (f32x4){0.f, 0.f, 0.f, 0.f};

    for (int k = 0; k < Ksplit; k += 32) {
        bf16x8 a = *(const bf16x8*)ap;
        ap += 32;
#pragma unroll
        for (int j = 0; j < 4; j++) {
            bf16x8 bfr = *(const bf16x8*)wp[j];
            wp[j] += 32;
            acc[j] = __builtin_amdgcn_mfma_f32_16x16x32_bf16(a, bfr, acc[j], 0, 0, 0);
        }
    }
#pragma unroll
    for (int j = 0; j < 4; j++) {
        int col = n0 + j * 16 + l16;
        if (col < Nw) {
#pragma unroll
            for (int r = 0; r < 4; r++) {
                int row = m0 + wid * 16 + quad * 4 + r;
                atomicAdd(outF + (size_t)row * 96 + col, acc[j][r]);
            }
        }
    }
}

// ---------------- delta GEMM: A = xd f32 (ld=96), softplus -> bf16 ----------------
__global__ __launch_bounds__(256) void gemm_dt(
    const float* __restrict__ A, const __bf16* __restrict__ W,
    const float* __restrict__ bias, u16* __restrict__ outB16) {
    int lane = threadIdx.x & 63;
    int wid  = threadIdx.x >> 6;
    int m0 = blockIdx.y * 64;
    int n0 = blockIdx.x * 64;
    int l16  = lane & 15;
    int quad = lane >> 4;
    int mrow = m0 + wid * 16 + l16;

    const float* ap = A + (size_t)mrow * 96 + quad * 8;
    const __bf16* wp[4];
#pragma unroll
    for (int j = 0; j < 4; j++) {
        int nc = n0 + j * 16 + l16;
        wp[j] = W + (size_t)nc * DT_RANK + quad * 8;
    }
    f32x4 acc[4];
#pragma unroll
    for (int j = 0; j < 4; j++) acc[j] = (f32x4){0.f, 0.f, 0.f, 0.f};

#pragma unroll
    for (int k = 0; k < DT_RANK; k += 32) {
        float4 v0 = *(const float4*)(ap);
        float4 v1 = *(const float4*)(ap + 4);
        ap += 32;
        u16x8 pk;
        pk[0] = f2bf(v0.x); pk[1] = f2bf(v0.y); pk[2] = f2bf(v0.z); pk[3] = f2bf(v0.w);
        pk[4] = f2bf(v1.x); pk[5] = f2bf(v1.y); pk[6] = f2bf(v1.z); pk[7] = f2bf(v1.w);
        bf16x8 a = __builtin_bit_cast(bf16x8, pk);
#pragma unroll
        for (int j = 0; j < 4; j++) {
            bf16x8 bfr = *(const bf16x8*)wp[j];
            wp[j] += 32;
            acc[j] = __builtin_amdgcn_mfma_f32_16x16x32_bf16(a, bfr, acc[j], 0, 0, 0);
        }
    }
#pragma unroll
    for (int j = 0; j < 4; j++) {
        int col = n0 + j * 16 + l16;
#pragma unroll
        for (int r = 0; r < 4; r++) {
            int row = m0 + wid * 16 + quad * 4 + r;
            float t = acc[j][r] + bias[col];
            float sp = (t > 20.f) ? t : log1pf(__expf(t));
            outB16[(size_t)row * D_INNER + col] = f2bf(sp);
        }
    }
}

// ---------------- causal depthwise conv + SiLU — LDS-tiled (R12 win) ----------------
#define XSLOTS 9   // row stride = 9 x 16B = 144B (16B-aligned rows, bank-spread)
__global__ __launch_bounds__(256) void conv_tile(
    const u16* __restrict__ xz, const float* __restrict__ cw,
    const float* __restrict__ cb, u16* __restrict__ uc) {
    __shared__ u16 Xs[35 * XSLOTS * 8];   // 5.04 KB (u16x8 slots)
    __shared__ float CW[4][64];           // 1 KB
    __shared__ float CB[64];              // 256 B
    int tid = threadIdx.x;
    int mt = blockIdx.x, b = blockIdx.z;
    int d0 = blockIdx.y * 64;
    int mbase = b * SEQ_L + mt * CHUNK;

    // stage xz u-half rows mbase-3 .. mbase+31 (35 rows x 8 x u16x8)
    for (int i = tid; i < 35 * 8; i += 256) {
        int s = i >> 3, slot = i & 7;
        u16x8 v = {0, 0, 0, 0, 0, 0, 0, 0};
        if (mt > 0 || s >= 3) {
            int m = mbase - 3 + s;
            v = *(const u16x8*)(xz + (size_t)m * (2 * D_INNER) + d0 + slot * 8);
        }
        *(u16x8*)(Xs + (s * XSLOTS + (slot ^ (s & 7))) * 8) = v;
    }
    if (tid < 64) {
        CB[tid] = cb[d0 + tid];
        float4 w = *(const float4*)(cw + (size_t)(d0 + tid) * 4);
        CW[0][tid] = w.x; CW[1][tid] = w.y; CW[2][tid] = w.z; CW[3][tid] = w.w;
    }
    __syncthreads();

    int r = tid >> 3;            // output row 0..31
    int slot = tid & 7;          // d-group
    int dbase = slot * 8;
    float s[8];
    {
        float4 b0 = *(const float4*)&CB[dbase];
        float4 b1 = *(const float4*)&CB[dbase + 4];
        s[0] = b0.x; s[1] = b0.y; s[2] = b0.z; s[3] = b0.w;
        s[4] = b1.x; s[5] = b1.y; s[6] = b1.z; s[7] = b1.w;
    }
#pragma unroll
    for (int j = 0; j < 4; j++) {
        int sr = r + j;          // staged row for tap j (global m = mbase + r - 3 + j)
        u16x8 xv = *(const u16x8*)(Xs + (sr * XSLOTS + (slot ^ (sr & 7))) * 8);
        float4 w0 = *(const float4*)&CW[j][dbase];
        float4 w1 = *(const float4*)&CW[j][dbase + 4];
        float wv[8] = {w0.x, w0.y, w0.z, w0.w, w1.x, w1.y, w1.z, w1.w};
#pragma unroll
        for (int q = 0; q < 8; q++) {
            s[q] += wv[q] * bf2f(xv[q]);
        }
    }
    u16x8 o;
#pragma unroll
    for (int q = 0; q < 8; q++) {
        float sig = 1.f / (1.f + __expf(-s[q]));
        o[q] = f2bf(s[q] * sig);
    }
    *(u16x8*)(uc + (size_t)(mbase + r) * D_INNER + d0 + dbase) = o;
}

// ================= chunked selective scan — CHUNK=32, LDS-staged inputs =================
// grid (NCHUNK=32, D_INNER/64, NBATCH) = 2048 blocks (8/CU).
__global__ __launch_bounds__(256) void scan_chunk(
    const u16* __restrict__ delta, const u16* __restrict__ uc,
    const float* __restrict__ xd, const float* __restrict__ A_log,
    float* __restrict__ Pst, float* __restrict__ Sst) {
    __shared__ float Bsh[CHUNK][16];   // 2 KB
    __shared__ u16 DLs[CHUNK][64];     // 4 KB
    __shared__ u16 UCs[CHUNK][64];     // 4 KB
    int tid  = threadIdx.x;
    int lane = tid & 63;
    int w    = tid >> 6;
    int dsub = lane & 15;
    int g    = lane >> 4;
    int n0   = g * 4;
    int c = blockIdx.x, b = blockIdx.z;
    int d0 = blockIdx.y * 64;
    int dloc = w * 16 + dsub;
    int d = d0 + dloc;
    int mbase = b * SEQ_L + c * CHUNK;

    {   // coalesced staging: 32 rows x 64 d x 2B per array; 8 thr/row x 16B = 128B/row
        int r = tid >> 3, c8 = (tid & 7) * 8;
        size_t gb = (size_t)(mbase + r) * D_INNER + d0 + c8;
        *(u16x8*)&DLs[r][c8] = *(const u16x8*)(delta + gb);
        *(u16x8*)&UCs[r][c8] = *(const u16x8*)(uc + gb);
    }
    if (tid < CHUNK * 4) {   // stage B rows: 32 x 16 floats
        int row = tid >> 2, q = tid & 3;
        *(float4*)&Bsh[row][q * 4] =
            *(const float4*)(xd + (size_t)(mbase + row) * 96 + DT_RANK + q * 4);
    }
    __syncthreads();

    float a[4];
    {
        float4 a0 = *(const float4*)(A_log + d * D_STATE + n0);
        a[0] = -__expf(a0.x); a[1] = -__expf(a0.y);
        a[2] = -__expf(a0.z); a[3] = -__expf(a0.w);
    }
    float P[4] = {1.f, 1.f, 1.f, 1.f}, S[4] = {0.f, 0.f, 0.f, 0.f};

    for (int t0 = 0; t0 < CHUNK; t0 += 4) {
        float dlv[4], uv[4];
#pragma unroll
        for (int i = 0; i < 4; i++) {
            dlv[i] = bf2f(DLs[t0 + i][dloc]);
            uv[i]  = bf2f(UCs[t0 + i][dloc]);
        }
#pragma unroll
        for (int i = 0; i < 4; i++) {
            float c1 = dlv[i] * uv[i];
#pragma unroll
            for (int j = 0; j < 4; j++) {
                float dA = __expf(dlv[i] * a[j]);
                P[j] *= dA;
                S[j] = dA * S[j] + c1 * Bsh[t0 + i][n0 + j];
            }
        }
    }
    size_t s = ((size_t)(b * D_INNER + d) * NCHUNK + c) * D_STATE + n0;
    *(float4*)(Pst + s) = (float4){P[0], P[1], P[2], P[3]};
    *(float4*)(Sst + s) = (float4){S[0], S[1], S[2], S[3]};
}

// scan_apply with FUSED combine prologue (CHUNK=32, same 2048-block geometry):
// each thread walks h = P*h + S over chunks 0..c-1 from L2-resident Pst/Sst —
// identical fold order to the old scan_combine (bit-identical numerics).
__global__ __launch_bounds__(256) void scan_apply(
    const u16* __restrict__ delta, const u16* __restrict__ uc,
    const float* __restrict__ xd, const u16* __restrict__ xz,
    const float* __restrict__ A_log, const float* __restrict__ Dsk,
    const float* __restrict__ Pst, const float* __restrict__ Sst,
    u16* __restrict__ yg) {
    __shared__ float BCs[CHUNK][32];   // 4 KB
    __shared__ u16 DLs[CHUNK][64];     // 4 KB
    __shared__ u16 UCs[CHUNK][64];     // 4 KB
    __shared__ u16 Zs[CHUNK][64];      // 4 KB
    int tid  = threadIdx.x;
    int lane = tid & 63;
    int w    = tid >> 6;
    int dsub = lane & 15;
    int g    = lane >> 4;
    int n0   = g * 4;
    int c = blockIdx.x, b = blockIdx.z;
    int d0 = blockIdx.y * 64;
    int dloc = w * 16 + dsub;
    int d = d0 + dloc;
    int mbase = b * SEQ_L + c * CHUNK;

    {   // coalesced staging of dl/uc/z tiles
        int r = tid >> 3, c8 = (tid & 7) * 8;
        size_t gb = (size_t)(mbase + r) * D_INNER + d0 + c8;
        *(u16x8*)&DLs[r][c8] = *(const u16x8*)(delta + gb);
        *(u16x8*)&UCs[r][c8] = *(const u16x8*)(uc + gb);
        *(u16x8*)&Zs[r][c8]  = *(const u16x8*)(
            xz + (size_t)(mbase + r) * (2 * D_INNER) + D_INNER + d0 + c8);
    }
    {   // stage B+C rows: 32 x 32 floats = 256 float4s
        int row = tid >> 3, q = tid & 7;
        *(float4*)&BCs[row][q * 4] =
            *(const float4*)(xd + (size_t)(mbase + row) * 96 + DT_RANK + q * 4);
    }

    // fused combine: chunk-prefix walk (runs while staging loads are in flight)
    float h[4] = {0.f, 0.f, 0.f, 0.f};
    {
        size_t base = ((size_t)(b * D_INNER + d) * NCHUNK) * D_STATE + n0;
        for (int cc = 0; cc < c; cc++) {
            float4 Pv = *(const float4*)(Pst + base + (size_t)cc * D_STATE);
            float4 Sv = *(const float4*)(Sst + base + (size_t)cc * D_STATE);
            h[0] = Pv.x * h[0] + Sv.x;
            h[1] = Pv.y * h[1] + Sv.y;
            h[2] = Pv.z * h[2] + Sv.z;
            h[3] = Pv.w * h[3] + Sv.w;
        }
    }

    float a[4];
    {
        float4 a0 = *(const float4*)(A_log + d * D_STATE + n0);
        a[0] = -__expf(a0.x); a[1] = -__expf(a0.y);
        a[2] = -__expf(a0.z); a[3] = -__expf(a0.w);
    }
    float dsk = Dsk[d];
    __syncthreads();

    for (int t0 = 0; t0 < CHUNK; t0 += 4) {
        float dlv[4], uv[4], zv[4];
#pragma unroll
        for (int i = 0; i < 4; i++) {
            dlv[i] = bf2f(DLs[t0 + i][dloc]);
            uv[i]  = bf2f(UCs[t0 + i][dloc]);
            zv[i]  = bf2f(Zs[t0 + i][dloc]);
        }
#pragma unroll
        for (int i = 0; i < 4; i++) {
            int t = t0 + i;
            float c1 = dlv[i] * uv[i];
            float y = 0.f;
#pragma unroll
            for (int j = 0; j < 4; j++) {
                float dA = __expf(dlv[i] * a[j]);
                h[j] = dA * h[j] + c1 * BCs[t][n0 + j];
                y += h[j] * BCs[t][16 + n0 + j];
            }
            y += __shfl_xor(y, 16);
            y += __shfl_xor(y, 32);
            if (g == 0) {
                float z = zv[i];
                float yv = y + uv[i] * dsk;
                float gt = z / (1.f + __expf(-z));
                yg[(size_t)(mbase + t) * D_INNER + d] = f2bf(yv * gt);
            }
        }
    }
}

extern "C" void kernel_launch(void* const* d_in, const int* in_sizes, int n_in,
                              void* d_out, int out_size, void* d_ws, size_t ws_size,
                              hipStream_t stream) {
    const float* x         = (const float*)d_in[0];
    const float* ln_g      = (const float*)d_in[1];
    const float* ln_b      = (const float*)d_in[2];
    const float* in_proj_w = (const float*)d_in[3];
    const float* conv_w    = (const float*)d_in[4];
    const float* conv_b    = (const float*)d_in[5];
    const float* x_proj_w  = (const float*)d_in[6];
    const float* dt_proj_w = (const float*)d_in[7];
    const float* dt_proj_b = (const float*)d_in[8];
    const float* A_log     = (const float*)d_in[9];
    const float* Dsk       = (const float*)d_in[10];
    const float* out_proj_w= (const float*)d_in[11];

    // ws is 256 MiB. Every buffer gets its own region — no overlays.
    char* ws = (char*)d_ws;
    u16* xn   = (u16*)ws;    ws += (size_t)M_ROWS * D_MODEL * 2;        // 4 MB
    u16* xz   = (u16*)ws;    ws += (size_t)M_ROWS * 2 * D_INNER * 2;    // 16 MB
    u16* ucv  = (u16*)ws;    ws += (size_t)M_ROWS * D_INNER * 2;        // 8 MB
    float* xd = (float*)ws;  ws += (size_t)M_ROWS * 96 * 4;             // 0.75 MB
    u16* dl   = (u16*)ws;    ws += (size_t)M_ROWS * D_INNER * 2;        // 8 MB (bf16)
    u16* yg   = (u16*)ws;    ws += (size_t)M_ROWS * D_INNER * 2;        // 8 MB
    u16* w_in = (u16*)ws;    ws += (size_t)4194304 * 2;                 // 8 MB
    u16* w_out= (u16*)ws;    ws += (size_t)2097152 * 2;                 // 4 MB
    u16* w_xp = (u16*)ws;    ws += (size_t)196608 * 2;                  // 0.375 MB
    u16* w_dt = (u16*)ws;    ws += (size_t)131072 * 2;                  // 0.25 MB
    float* Pst = (float*)ws; ws += (size_t)NBATCH * D_INNER * D_STATE * NCHUNK * 4; // 8 MB
    float* Sst = (float*)ws; ws += (size_t)NBATCH * D_INNER * D_STATE * NCHUNK * 4; // 8 MB
    float* opart = (float*)ws;                                          // 32 MB

    // 0. scalar weight casts + xd zero + LayerNorm — one dispatch
    prep<<<26048 + M_ROWS, 256, 0, stream>>>(
        in_proj_w, out_proj_w, x_proj_w, dt_proj_w, w_in, w_out, w_xp, w_dt,
        x, ln_g, ln_b, xn, xd);
    // 1. xz = xn @ in_proj_w^T — 2-phase pipelined 64x128 tile, 1024 blocks (4/CU)
    gemm_lds<64, 128, 4, 2, 0><<<dim3(4096 / 128, M_ROWS / 64, 1), 256, 0, stream>>>(
        (const __bf16*)xn, (const __bf16*)w_in, D_MODEL, D_MODEL / 32, 2 * D_INNER,
        nullptr, xz);
    // 2. causal depthwise conv + SiLU — LDS-tiled, 2048 blocks (8/CU)
    conv_tile<<<dim3(SEQ_L / CHUNK, D_INNER / 64, NBATCH), 256, 0, stream>>>(
        xz, conv_w, conv_b, ucv);
    // 3. x_dbl = u @ x_proj_w^T  (N=96), K-split x8 via f32 atomics into L2-resident xd
    gemm_xp<<<dim3(2, 32, 8), 256, 0, stream>>>(
        (const __bf16*)ucv, (const __bf16*)w_xp, xd);
    // 4. delta = softplus(xd[:, :64] @ dt_proj_w^T + dt_proj_b) -> bf16 (f32 A-read)
    gemm_dt<<<dim3(32, 32, 1), 256, 0, stream>>>(
        xd, (const __bf16*)w_dt, dt_proj_b, dl);
    // 5. chunked scan: chunk pass + apply-with-fused-combine (2 dispatches, 2048 blocks each)
    dim3 sgrid(NCHUNK, D_INNER / 64, NBATCH);
    scan_chunk<<<sgrid, 256, 0, stream>>>(dl, ucv, xd, A_log, Pst, Sst);
    scan_apply<<<sgrid, 256, 0, stream>>>(dl, ucv, xd, xz, A_log, Dsk, Pst, Sst, yg);
    // 6. out_proj partials — 2-phase pipelined (K=2048 split x4, 512 blocks 2/CU) + reduce
    gemm_lds<64, 128, 4, 2, 4><<<dim3(1024 / 128, M_ROWS / 64, 4), 256, 0, stream>>>(
        (const __bf16*)yg, (const __bf16*)w_out, D_INNER, D_INNER / 4 / 32, D_MODEL,
        opart, nullptr);
    out_reduce<<<(M_ROWS * D_MODEL / 4) / 256, 256, 0, stream>>>(
        opart, x, (float*)d_out);
}

// Round 17
// 244.656 us; speedup vs baseline: 1.1581x; 1.1581x over previous
//
#include <hip/hip_runtime.h>

#define D_MODEL 1024
#define D_STATE 16
#define D_INNER 2048
#define DT_RANK 64
#define NBATCH 2
#define SEQ_L 1024
#define M_ROWS (NBATCH * SEQ_L)   // 2048
#define CHUNK 32
#define NCHUNK (SEQ_L / CHUNK)    // 32

typedef __bf16 bf16x8 __attribute__((ext_vector_type(8)));
typedef float f32x4 __attribute__((ext_vector_type(4)));
typedef unsigned short u16;
typedef unsigned int u32;
typedef u16 u16x4 __attribute__((ext_vector_type(4)));
typedef u16 u16x8 __attribute__((ext_vector_type(8)));

__device__ __forceinline__ float bf2f(u16 h) {
    return __uint_as_float(((unsigned)h) << 16);
}
__device__ __forceinline__ u16 f2bf(float f) {
    unsigned u = __float_as_uint(f);
    u += 0x7fff + ((u >> 16) & 1);   // round-to-nearest-even
    return (u16)(u >> 16);
}

// ---------------- prep: float4 weight casts + xd zero + LayerNorm ----------------
// cast boundaries in float4 units: in_proj 1048576, +out 1572864, +xp 1622016, +dt 1654784
// blocks [0,6464): vec4 casts; [6464,6656): zero xd; rest: LN rows
__global__ __launch_bounds__(256) void prep(
    const float* __restrict__ s0, const float* __restrict__ s1,
    const float* __restrict__ s2, const float* __restrict__ s3,
    u16* __restrict__ d0, u16* __restrict__ d1,
    u16* __restrict__ d2, u16* __restrict__ d3,
    const float* __restrict__ x, const float* __restrict__ g,
    const float* __restrict__ b, u16* __restrict__ xn,
    float* __restrict__ xd) {
    int blk = blockIdx.x;
    if (blk < 6464) {
        int idx = blk * 256 + threadIdx.x;   // float4 index
        const float4* s; u16* dp; int i;
        if (idx < 1048576)      { s = (const float4*)s0; i = idx;           dp = d0; }
        else if (idx < 1572864) { s = (const float4*)s1; i = idx - 1048576; dp = d1; }
        else if (idx < 1622016) { s = (const float4*)s2; i = idx - 1572864; dp = d2; }
        else                    { s = (const float4*)s3; i = idx - 1622016; dp = d3; }
        float4 v = s[i];
        u16x4 o = {f2bf(v.x), f2bf(v.y), f2bf(v.z), f2bf(v.w)};
        *(u16x4*)(dp + (size_t)i * 4) = o;
        return;
    }
    if (blk < 6656) {
        int zi = (blk - 6464) * 256 + threadIdx.x;   // float4 index < 49152
        ((float4*)xd)[zi] = (float4){0.f, 0.f, 0.f, 0.f};
        return;
    }
    int row = blk - 6656;
    const float4* xr = (const float4*)(x + (size_t)row * D_MODEL);
    float4 v = xr[threadIdx.x];
    float s  = v.x + v.y + v.z + v.w;
    float ss = v.x * v.x + v.y * v.y + v.z * v.z + v.w * v.w;
#pragma unroll
    for (int off = 32; off > 0; off >>= 1) {
        s  += __shfl_down(s,  off, 64);
        ss += __shfl_down(ss, off, 64);
    }
    __shared__ float sh_s[4], sh_ss[4];
    int wid = threadIdx.x >> 6;
    if ((threadIdx.x & 63) == 0) { sh_s[wid] = s; sh_ss[wid] = ss; }
    __syncthreads();
    float mu  = (sh_s[0] + sh_s[1] + sh_s[2] + sh_s[3]) * (1.0f / D_MODEL);
    float var = (sh_ss[0] + sh_ss[1] + sh_ss[2] + sh_ss[3]) * (1.0f / D_MODEL) - mu * mu;
    float rs = rsqrtf(var + 1e-5f);
    int c0 = threadIdx.x * 4;
    float vv[4] = {v.x, v.y, v.z, v.w};
#pragma unroll
    for (int j = 0; j < 4; j++) {
        int c = c0 + j;
        float o = (vv[j] - mu) * rs * g[c] + b[c];
        xn[(size_t)row * D_MODEL + c] = f2bf(o);
    }
}

// ============ LDS-staged B^T GEMM — 2-phase double-buffered pipeline (R15) ============
// MODE 0: bf16 store. MODE 4: f32 partial store to outF + z*M_ROWS*ldC.
template <int BM, int BN, int WM, int WN, int MODE>
__global__ __launch_bounds__(256) void gemm_lds(
    const __bf16* __restrict__ A, const __bf16* __restrict__ W,
    int K, int Ksteps, int ldC,
    float* __restrict__ outF, u16* __restrict__ outB) {
    constexpr int WCOLS = BN / (WN * 16);
    __shared__ __bf16 As[2][BM * 32];
    __shared__ __bf16 Bs[2][BN * 32];
    int tid  = threadIdx.x;
    int lane = tid & 63;
    int wid  = tid >> 6;
    int l16  = lane & 15;
    int quad = lane >> 4;
    int wr = wid / WCOLS;
    int wc = wid % WCOLS;
    int m0 = blockIdx.y * BM;
    int n0 = blockIdx.x * BN;
    int kbase = blockIdx.z * Ksteps * 32;

    f32x4 acc[WM][WN];
#pragma unroll
    for (int mi = 0; mi < WM; mi++)
#pragma unroll
        for (int nj = 0; nj < WN; nj++)
            acc[mi][nj] = (f32x4){0.f, 0.f, 0.f, 0.f};

    auto STAGE = [&](int buf, int ki) {
        int k0 = kbase + ki * 32;
#pragma unroll
        for (int i = 0; i < BM / 64; i++) {
            int t   = i * 256 + tid;
            int row = t >> 2;
            int cg  = (t & 3) ^ ((row >> 1) & 3);
            __builtin_amdgcn_global_load_lds(
                (const __attribute__((address_space(1))) u32*)(A + (size_t)(m0 + row) * K + k0 + cg * 8),
                (__attribute__((address_space(3))) u32*)(As[buf] + (i * 256 + wid * 64) * 8),
                16, 0, 0);
        }
#pragma unroll
        for (int i = 0; i < BN / 64; i++) {
            int t   = i * 256 + tid;
            int row = t >> 2;
            int cg  = (t & 3) ^ ((row >> 1) & 3);
            __builtin_amdgcn_global_load_lds(
                (const __attribute__((address_space(1))) u32*)(W + (size_t)(n0 + row) * K + k0 + cg * 8),
                (__attribute__((address_space(3))) u32*)(Bs[buf] + (i * 256 + wid * 64) * 8),
                16, 0, 0);
        }
    };

    STAGE(0, 0);
    __syncthreads();   // prologue: buf0 ready

    int cur = 0;
    for (int ki = 0; ki < Ksteps; ki++) {
        if (ki + 1 < Ksteps) STAGE(cur ^ 1, ki + 1);   // prefetch flies under compute

        bf16x8 af[WM], bfr[WN];
#pragma unroll
        for (int mi = 0; mi < WM; mi++) {
            int r  = wr * WM * 16 + mi * 16 + l16;
            int cg = quad ^ ((r >> 1) & 3);
            af[mi] = *(const bf16x8*)(As[cur] + r * 32 + cg * 8);
        }
#pragma unroll
        for (int nj = 0; nj < WN; nj++) {
            int r  = wc * WN * 16 + nj * 16 + l16;
            int cg = quad ^ ((r >> 1) & 3);
            bfr[nj] = *(const bf16x8*)(Bs[cur] + r * 32 + cg * 8);
        }
#pragma unroll
        for (int mi = 0; mi < WM; mi++)
#pragma unroll
            for (int nj = 0; nj < WN; nj++)
                acc[mi][nj] = __builtin_amdgcn_mfma_f32_16x16x32_bf16(
                    af[mi], bfr[nj], acc[mi][nj], 0, 0, 0);

        __syncthreads();   // drains prefetch (vmcnt0) + all waves done reading cur
        cur ^= 1;
    }

    float* outP = (MODE == 4) ? outF + (size_t)blockIdx.z * M_ROWS * ldC : outF;
#pragma unroll
    for (int mi = 0; mi < WM; mi++) {
#pragma unroll
        for (int nj = 0; nj < WN; nj++) {
            int col = n0 + wc * WN * 16 + nj * 16 + l16;
#pragma unroll
            for (int r = 0; r < 4; r++) {
                int row = m0 + wr * WM * 16 + mi * 16 + quad * 4 + r;
                float v = acc[mi][nj][r];
                if (MODE == 0) {
                    outB[(size_t)row * ldC + col] = f2bf(v);
                } else {
                    outP[(size_t)row * ldC + col] = v;
                }
            }
        }
    }
}

// ---------------- out_proj partial reduce (4 partials) + residual ----------------
__global__ __launch_bounds__(256) void out_reduce(
    const float* __restrict__ p, const float* __restrict__ x,
    float* __restrict__ out) {
    int idx = blockIdx.x * 256 + threadIdx.x;   // float4 index
    const int N = M_ROWS * D_MODEL;
    float4 a = ((const float4*)p)[idx];
    float4 b = ((const float4*)(p + N))[idx];
    float4 c = ((const float4*)(p + 2 * N))[idx];
    float4 d = ((const float4*)(p + 3 * N))[idx];
    float4 r = ((const float4*)x)[idx];
    float4 o;
    o.x = a.x + b.x + c.x + d.x + r.x;
    o.y = a.y + b.y + c.y + d.y + r.y;
    o.z = a.z + b.z + c.z + d.z + r.z;
    o.w = a.w + b.w + c.w + d.w + r.w;
    ((float4*)out)[idx] = o;
}

// ---------------- x_proj GEMM: K-split partials accumulated via f32 atomicAdd ----------------
// xd pre-zeroed in prep (0.75 MB, L2-resident). grid (2, 32, 8).
__global__ __launch_bounds__(256) void gemm_xp(
    const __bf16* __restrict__ A, const __bf16* __restrict__ W,
    float* __restrict__ outF) {
    const int K = D_INNER, Ksplit = D_INNER / 8, Nw = 96;
    int lane = threadIdx.x & 63;
    int wid  = threadIdx.x >> 6;
    int m0 = blockIdx.y * 64;
    int n0 = blockIdx.x * 64;
    int kc = blockIdx.z;
    int l16  = lane & 15;
    int quad = lane >> 4;
    int mrow = m0 + wid * 16 + l16;

    const __bf16* ap = A + (size_t)mrow * K + kc * Ksplit + quad * 8;
    const __bf16* wp[4];
#pragma unroll
    for (int j = 0; j < 4; j++) {
        int nc = n0 + j * 16 + l16;
        if (nc > Nw - 1) nc = Nw - 1;
        wp[j] = W + (size_t)nc * K + kc * Ksplit + quad * 8;
    }
    f32x4 acc[4];
#pragma unroll
    for (int j = 0; j < 4; j++) acc[j] = (f32x4){0.f, 0.f, 0.f, 0.f};

    for (int k = 0; k < Ksplit; k += 32) {
        bf16x8 a = *(const bf16x8*)ap;
        ap += 32;
#pragma unroll
        for (int j = 0; j < 4; j++) {
            bf16x8 bfr = *(const bf16x8*)wp[j];
            wp[j] += 32;
            acc[j] = __builtin_amdgcn_mfma_f32_16x16x32_bf16(a, bfr, acc[j], 0, 0, 0);
        }
    }
#pragma unroll
    for (int j = 0; j < 4; j++) {
        int col = n0 + j * 16 + l16;
        if (col < Nw) {
#pragma unroll
            for (int r = 0; r < 4; r++) {
                int row = m0 + wid * 16 + quad * 4 + r;
                atomicAdd(outF + (size_t)row * 96 + col, acc[j][r]);
            }
        }
    }
}

// ---------------- delta GEMM: A = xd f32 (ld=96), softplus -> bf16 ----------------
__global__ __launch_bounds__(256) void gemm_dt(
    const float* __restrict__ A, const __bf16* __restrict__ W,
    const float* __restrict__ bias, u16* __restrict__ outB16) {
    int lane = threadIdx.x & 63;
    int wid  = threadIdx.x >> 6;
    int m0 = blockIdx.y * 64;
    int n0 = blockIdx.x * 64;
    int l16  = lane & 15;
    int quad = lane >> 4;
    int mrow = m0 + wid * 16 + l16;

    const float* ap = A + (size_t)mrow * 96 + quad * 8;
    const __bf16* wp[4];
#pragma unroll
    for (int j = 0; j < 4; j++) {
        int nc = n0 + j * 16 + l16;
        wp[j] = W + (size_t)nc * DT_RANK + quad * 8;
    }
    f32x4 acc[4];
#pragma unroll
    for (int j = 0; j < 4; j++) acc[j] = (f32x4){0.f, 0.f, 0.f, 0.f};

#pragma unroll
    for (int k = 0; k < DT_RANK; k += 32) {
        float4 v0 = *(const float4*)(ap);
        float4 v1 = *(const float4*)(ap + 4);
        ap += 32;
        u16x8 pk;
        pk[0] = f2bf(v0.x); pk[1] = f2bf(v0.y); pk[2] = f2bf(v0.z); pk[3] = f2bf(v0.w);
        pk[4] = f2bf(v1.x); pk[5] = f2bf(v1.y); pk[6] = f2bf(v1.z); pk[7] = f2bf(v1.w);
        bf16x8 a = __builtin_bit_cast(bf16x8, pk);
#pragma unroll
        for (int j = 0; j < 4; j++) {
            bf16x8 bfr = *(const bf16x8*)wp[j];
            wp[j] += 32;
            acc[j] = __builtin_amdgcn_mfma_f32_16x16x32_bf16(a, bfr, acc[j], 0, 0, 0);
        }
    }
#pragma unroll
    for (int j = 0; j < 4; j++) {
        int col = n0 + j * 16 + l16;
#pragma unroll
        for (int r = 0; r < 4; r++) {
            int row = m0 + wid * 16 + quad * 4 + r;
            float t = acc[j][r] + bias[col];
            float sp = (t > 20.f) ? t : log1pf(__expf(t));
            outB16[(size_t)row * D_INNER + col] = f2bf(sp);
        }
    }
}

// ---------------- causal depthwise conv + SiLU — LDS-tiled (R12 win) ----------------
#define XSLOTS 9   // row stride = 9 x 16B = 144B (16B-aligned rows, bank-spread)
__global__ __launch_bounds__(256) void conv_tile(
    const u16* __restrict__ xz, const float* __restrict__ cw,
    const float* __restrict__ cb, u16* __restrict__ uc) {
    __shared__ u16 Xs[35 * XSLOTS * 8];   // 5.04 KB (u16x8 slots)
    __shared__ float CW[4][64];           // 1 KB
    __shared__ float CB[64];              // 256 B
    int tid = threadIdx.x;
    int mt = blockIdx.x, b = blockIdx.z;
    int d0 = blockIdx.y * 64;
    int mbase = b * SEQ_L + mt * CHUNK;

    // stage xz u-half rows mbase-3 .. mbase+31 (35 rows x 8 x u16x8)
    for (int i = tid; i < 35 * 8; i += 256) {
        int s = i >> 3, slot = i & 7;
        u16x8 v = {0, 0, 0, 0, 0, 0, 0, 0};
        if (mt > 0 || s >= 3) {
            int m = mbase - 3 + s;
            v = *(const u16x8*)(xz + (size_t)m * (2 * D_INNER) + d0 + slot * 8);
        }
        *(u16x8*)(Xs + (s * XSLOTS + (slot ^ (s & 7))) * 8) = v;
    }
    if (tid < 64) {
        CB[tid] = cb[d0 + tid];
        float4 w = *(const float4*)(cw + (size_t)(d0 + tid) * 4);
        CW[0][tid] = w.x; CW[1][tid] = w.y; CW[2][tid] = w.z; CW[3][tid] = w.w;
    }
    __syncthreads();

    int r = tid >> 3;            // output row 0..31
    int slot = tid & 7;          // d-group
    int dbase = slot * 8;
    float s[8];
    {
        float4 b0 = *(const float4*)&CB[dbase];
        float4 b1 = *(const float4*)&CB[dbase + 4];
        s[0] = b0.x; s[1] = b0.y; s[2] = b0.z; s[3] = b0.w;
        s[4] = b1.x; s[5] = b1.y; s[6] = b1.z; s[7] = b1.w;
    }
#pragma unroll
    for (int j = 0; j < 4; j++) {
        int sr = r + j;          // staged row for tap j (global m = mbase + r - 3 + j)
        u16x8 xv = *(const u16x8*)(Xs + (sr * XSLOTS + (slot ^ (sr & 7))) * 8);
        float4 w0 = *(const float4*)&CW[j][dbase];
        float4 w1 = *(const float4*)&CW[j][dbase + 4];
        float wv[8] = {w0.x, w0.y, w0.z, w0.w, w1.x, w1.y, w1.z, w1.w};
#pragma unroll
        for (int q = 0; q < 8; q++) {
            s[q] += wv[q] * bf2f(xv[q]);
        }
    }
    u16x8 o;
#pragma unroll
    for (int q = 0; q < 8; q++) {
        float sig = 1.f / (1.f + __expf(-s[q]));
        o[q] = f2bf(s[q] * sig);
    }
    *(u16x8*)(uc + (size_t)(mbase + r) * D_INNER + d0 + dbase) = o;
}

// ================= chunked selective scan — CHUNK=32, LDS-staged inputs =================
// grid (NCHUNK=32, D_INNER/64, NBATCH) = 2048 blocks (8/CU).
__global__ __launch_bounds__(256) void scan_chunk(
    const u16* __restrict__ delta, const u16* __restrict__ uc,
    const float* __restrict__ xd, const float* __restrict__ A_log,
    float* __restrict__ Pst, float* __restrict__ Sst) {
    __shared__ float Bsh[CHUNK][16];   // 2 KB
    __shared__ u16 DLs[CHUNK][64];     // 4 KB
    __shared__ u16 UCs[CHUNK][64];     // 4 KB
    int tid  = threadIdx.x;
    int lane = tid & 63;
    int w    = tid >> 6;
    int dsub = lane & 15;
    int g    = lane >> 4;
    int n0   = g * 4;
    int c = blockIdx.x, b = blockIdx.z;
    int d0 = blockIdx.y * 64;
    int dloc = w * 16 + dsub;
    int d = d0 + dloc;
    int mbase = b * SEQ_L + c * CHUNK;

    {   // coalesced staging: 32 rows x 64 d x 2B per array; 8 thr/row x 16B = 128B/row
        int r = tid >> 3, c8 = (tid & 7) * 8;
        size_t gb = (size_t)(mbase + r) * D_INNER + d0 + c8;
        *(u16x8*)&DLs[r][c8] = *(const u16x8*)(delta + gb);
        *(u16x8*)&UCs[r][c8] = *(const u16x8*)(uc + gb);
    }
    if (tid < CHUNK * 4) {   // stage B rows: 32 x 16 floats
        int row = tid >> 2, q = tid & 3;
        *(float4*)&Bsh[row][q * 4] =
            *(const float4*)(xd + (size_t)(mbase + row) * 96 + DT_RANK + q * 4);
    }
    __syncthreads();

    float a[4];
    {
        float4 a0 = *(const float4*)(A_log + d * D_STATE + n0);
        a[0] = -__expf(a0.x); a[1] = -__expf(a0.y);
        a[2] = -__expf(a0.z); a[3] = -__expf(a0.w);
    }
    float P[4] = {1.f, 1.f, 1.f, 1.f}, S[4] = {0.f, 0.f, 0.f, 0.f};

    for (int t0 = 0; t0 < CHUNK; t0 += 4) {
        float dlv[4], uv[4];
#pragma unroll
        for (int i = 0; i < 4; i++) {
            dlv[i] = bf2f(DLs[t0 + i][dloc]);
            uv[i]  = bf2f(UCs[t0 + i][dloc]);
        }
#pragma unroll
        for (int i = 0; i < 4; i++) {
            float c1 = dlv[i] * uv[i];
#pragma unroll
            for (int j = 0; j < 4; j++) {
                float dA = __expf(dlv[i] * a[j]);
                P[j] *= dA;
                S[j] = dA * S[j] + c1 * Bsh[t0 + i][n0 + j];
            }
        }
    }
    size_t s = ((size_t)(b * D_INNER + d) * NCHUNK + c) * D_STATE + n0;
    *(float4*)(Pst + s) = (float4){P[0], P[1], P[2], P[3]};
    *(float4*)(Sst + s) = (float4){S[0], S[1], S[2], S[3]};
}

__global__ __launch_bounds__(256) void scan_combine(
    const float* __restrict__ Pst, const float* __restrict__ Sst,
    float* __restrict__ Hin) {
    int idx = blockIdx.x * 256 + threadIdx.x;   // < NBATCH*D_INNER*D_STATE
    int bd = idx >> 4;
    int n  = idx & 15;
    float h = 0.f;
#pragma unroll
    for (int c = 0; c < NCHUNK; ++c) {
        size_t s = ((size_t)bd * NCHUNK + c) * D_STATE + n;
        Hin[s] = h;
        h = Pst[s] * h + Sst[s];
    }
}

__global__ __launch_bounds__(256) void scan_apply(
    const u16* __restrict__ delta, const u16* __restrict__ uc,
    const float* __restrict__ xd, const u16* __restrict__ xz,
    const float* __restrict__ A_log, const float* __restrict__ Dsk,
    const float* __restrict__ Hin, u16* __restrict__ yg) {
    __shared__ float BCs[CHUNK][32];   // 4 KB
    __shared__ u16 DLs[CHUNK][64];     // 4 KB
    __shared__ u16 UCs[CHUNK][64];     // 4 KB
    __shared__ u16 Zs[CHUNK][64];      // 4 KB
    int tid  = threadIdx.x;
    int lane = tid & 63;
    int w    = tid >> 6;
    int dsub = lane & 15;
    int g    = lane >> 4;
    int n0   = g * 4;
    int c = blockIdx.x, b = blockIdx.z;
    int d0 = blockIdx.y * 64;
    int dloc = w * 16 + dsub;
    int d = d0 + dloc;
    int mbase = b * SEQ_L + c * CHUNK;

    {   // coalesced staging of dl/uc/z tiles
        int r = tid >> 3, c8 = (tid & 7) * 8;
        size_t gb = (size_t)(mbase + r) * D_INNER + d0 + c8;
        *(u16x8*)&DLs[r][c8] = *(const u16x8*)(delta + gb);
        *(u16x8*)&UCs[r][c8] = *(const u16x8*)(uc + gb);
        *(u16x8*)&Zs[r][c8]  = *(const u16x8*)(
            xz + (size_t)(mbase + r) * (2 * D_INNER) + D_INNER + d0 + c8);
    }
    {   // stage B+C rows: 32 x 32 floats = 256 float4s
        int row = tid >> 3, q = tid & 7;
        *(float4*)&BCs[row][q * 4] =
            *(const float4*)(xd + (size_t)(mbase + row) * 96 + DT_RANK + q * 4);
    }
    __syncthreads();

    float a[4];
    {
        float4 a0 = *(const float4*)(A_log + d * D_STATE + n0);
        a[0] = -__expf(a0.x); a[1] = -__expf(a0.y);
        a[2] = -__expf(a0.z); a[3] = -__expf(a0.w);
    }
    float h[4];
    {
        float4 h0 = *(const float4*)(Hin +
            (((size_t)(b * D_INNER + d) * NCHUNK + c) * D_STATE + n0));
        h[0] = h0.x; h[1] = h0.y; h[2] = h0.z; h[3] = h0.w;
    }
    float dsk = Dsk[d];

    for (int t0 = 0; t0 < CHUNK; t0 += 4) {
        float dlv[4], uv[4], zv[4];
#pragma unroll
        for (int i = 0; i < 4; i++) {
            dlv[i] = bf2f(DLs[t0 + i][dloc]);
            uv[i]  = bf2f(UCs[t0 + i][dloc]);
            zv[i]  = bf2f(Zs[t0 + i][dloc]);
        }
#pragma unroll
        for (int i = 0; i < 4; i++) {
            int t = t0 + i;
            float c1 = dlv[i] * uv[i];
            float y = 0.f;
#pragma unroll
            for (int j = 0; j < 4; j++) {
                float dA = __expf(dlv[i] * a[j]);
                h[j] = dA * h[j] + c1 * BCs[t][n0 + j];
                y += h[j] * BCs[t][16 + n0 + j];
            }
            y += __shfl_xor(y, 16);
            y += __shfl_xor(y, 32);
            if (g == 0) {
                float z = zv[i];
                float yv = y + uv[i] * dsk;
                float gt = z / (1.f + __expf(-z));
                yg[(size_t)(mbase + t) * D_INNER + d] = f2bf(yv * gt);
            }
        }
    }
}

extern "C" void kernel_launch(void* const* d_in, const int* in_sizes, int n_in,
                              void* d_out, int out_size, void* d_ws, size_t ws_size,
                              hipStream_t stream) {
    const float* x         = (const float*)d_in[0];
    const float* ln_g      = (const float*)d_in[1];
    const float* ln_b      = (const float*)d_in[2];
    const float* in_proj_w = (const float*)d_in[3];
    const float* conv_w    = (const float*)d_in[4];
    const float* conv_b    = (const float*)d_in[5];
    const float* x_proj_w  = (const float*)d_in[6];
    const float* dt_proj_w = (const float*)d_in[7];
    const float* dt_proj_b = (const float*)d_in[8];
    const float* A_log     = (const float*)d_in[9];
    const float* Dsk       = (const float*)d_in[10];
    const float* out_proj_w= (const float*)d_in[11];

    // ws is 256 MiB. Every buffer gets its own region — no overlays.
    char* ws = (char*)d_ws;
    u16* xn   = (u16*)ws;    ws += (size_t)M_ROWS * D_MODEL * 2;        // 4 MB
    u16* xz   = (u16*)ws;    ws += (size_t)M_ROWS * 2 * D_INNER * 2;    // 16 MB
    u16* ucv  = (u16*)ws;    ws += (size_t)M_ROWS * D_INNER * 2;        // 8 MB
    float* xd = (float*)ws;  ws += (size_t)M_ROWS * 96 * 4;             // 0.75 MB
    u16* dl   = (u16*)ws;    ws += (size_t)M_ROWS * D_INNER * 2;        // 8 MB (bf16)
    u16* yg   = (u16*)ws;    ws += (size_t)M_ROWS * D_INNER * 2;        // 8 MB
    u16* w_in = (u16*)ws;    ws += (size_t)4194304 * 2;                 // 8 MB
    u16* w_out= (u16*)ws;    ws += (size_t)2097152 * 2;                 // 4 MB
    u16* w_xp = (u16*)ws;    ws += (size_t)196608 * 2;                  // 0.375 MB
    u16* w_dt = (u16*)ws;    ws += (size_t)131072 * 2;                  // 0.25 MB
    float* Pst = (float*)ws; ws += (size_t)NBATCH * D_INNER * D_STATE * NCHUNK * 4; // 8 MB
    float* Sst = (float*)ws; ws += (size_t)NBATCH * D_INNER * D_STATE * NCHUNK * 4; // 8 MB
    float* Hin = (float*)ws; ws += (size_t)NBATCH * D_INNER * D_STATE * NCHUNK * 4; // 8 MB
    float* opart = (float*)ws;                                          // 32 MB

    // 0. float4 weight casts + xd zero + LayerNorm — one dispatch
    prep<<<6656 + M_ROWS, 256, 0, stream>>>(
        in_proj_w, out_proj_w, x_proj_w, dt_proj_w, w_in, w_out, w_xp, w_dt,
        x, ln_g, ln_b, xn, xd);
    // 1. xz = xn @ in_proj_w^T — 2-phase pipelined 64x128 tile, 1024 blocks (4/CU)
    gemm_lds<64, 128, 4, 2, 0><<<dim3(4096 / 128, M_ROWS / 64, 1), 256, 0, stream>>>(
        (const __bf16*)xn, (const __bf16*)w_in, D_MODEL, D_MODEL / 32, 2 * D_INNER,
        nullptr, xz);
    // 2. causal depthwise conv + SiLU — LDS-tiled, 2048 blocks (8/CU)
    conv_tile<<<dim3(SEQ_L / CHUNK, D_INNER / 64, NBATCH), 256, 0, stream>>>(
        xz, conv_w, conv_b, ucv);
    // 3. x_dbl = u @ x_proj_w^T  (N=96), K-split x8 via f32 atomics into L2-resident xd
    gemm_xp<<<dim3(2, 32, 8), 256, 0, stream>>>(
        (const __bf16*)ucv, (const __bf16*)w_xp, xd);
    // 4. delta = softplus(xd[:, :64] @ dt_proj_w^T + dt_proj_b) -> bf16 (f32 A-read)
    gemm_dt<<<dim3(32, 32, 1), 256, 0, stream>>>(
        xd, (const __bf16*)w_dt, dt_proj_b, dl);
    // 5. chunked selective scan trio (CHUNK=32, 2048 blocks, 8/CU) — LDS-staged inputs
    dim3 sgrid(NCHUNK, D_INNER / 64, NBATCH);
    scan_chunk<<<sgrid, 256, 0, stream>>>(dl, ucv, xd, A_log, Pst, Sst);
    scan_combine<<<(NBATCH * D_INNER * D_STATE) / 256, 256, 0, stream>>>(Pst, Sst, Hin);
    scan_apply<<<sgrid, 256, 0, stream>>>(dl, ucv, xd, xz, A_log, Dsk, Hin, yg);
    // 6. out_proj partials — 2-phase pipelined (K=2048 split x4, 512 blocks 2/CU) + reduce
    gemm_lds<64, 128, 4, 2, 4><<<dim3(1024 / 128, M_ROWS / 64, 4), 256, 0, stream>>>(
        (const __bf16*)yg, (const __bf16*)w_out, D_INNER, D_INNER / 4 / 32, D_MODEL,
        opart, nullptr);
    out_reduce<<<(M_ROWS * D_MODEL / 4) / 256, 256, 0, stream>>>(
        opart, x, (float*)d_out);
}

// Round 18
// 241.415 us; speedup vs baseline: 1.1737x; 1.0134x over previous
//
#include <hip/hip_runtime.h>

#define D_MODEL 1024
#define D_STATE 16
#define D_INNER 2048
#define DT_RANK 64
#define NBATCH 2
#define SEQ_L 1024
#define M_ROWS (NBATCH * SEQ_L)   // 2048
#define CHUNK 32
#define NCHUNK (SEQ_L / CHUNK)    // 32

typedef __bf16 bf16x8 __attribute__((ext_vector_type(8)));
typedef float f32x4 __attribute__((ext_vector_type(4)));
typedef unsigned short u16;
typedef unsigned int u32;
typedef u16 u16x4 __attribute__((ext_vector_type(4)));
typedef u16 u16x8 __attribute__((ext_vector_type(8)));

__device__ __forceinline__ float bf2f(u16 h) {
    return __uint_as_float(((unsigned)h) << 16);
}
__device__ __forceinline__ u16 f2bf(float f) {
    unsigned u = __float_as_uint(f);
    u += 0x7fff + ((u >> 16) & 1);   // round-to-nearest-even
    return (u16)(u >> 16);
}

// ---------------- prep: float4 weight casts + xd zero + LayerNorm ----------------
// blocks [0,6464): vec4 casts; [6464,6656): zero xd; rest: LN rows
__global__ __launch_bounds__(256) void prep(
    const float* __restrict__ s0, const float* __restrict__ s1,
    const float* __restrict__ s2, const float* __restrict__ s3,
    u16* __restrict__ d0, u16* __restrict__ d1,
    u16* __restrict__ d2, u16* __restrict__ d3,
    const float* __restrict__ x, const float* __restrict__ g,
    const float* __restrict__ b, u16* __restrict__ xn,
    float* __restrict__ xd) {
    int blk = blockIdx.x;
    if (blk < 6464) {
        int idx = blk * 256 + threadIdx.x;   // float4 index
        const float4* s; u16* dp; int i;
        if (idx < 1048576)      { s = (const float4*)s0; i = idx;           dp = d0; }
        else if (idx < 1572864) { s = (const float4*)s1; i = idx - 1048576; dp = d1; }
        else if (idx < 1622016) { s = (const float4*)s2; i = idx - 1572864; dp = d2; }
        else                    { s = (const float4*)s3; i = idx - 1622016; dp = d3; }
        float4 v = s[i];
        u16x4 o = {f2bf(v.x), f2bf(v.y), f2bf(v.z), f2bf(v.w)};
        *(u16x4*)(dp + (size_t)i * 4) = o;
        return;
    }
    if (blk < 6656) {
        int zi = (blk - 6464) * 256 + threadIdx.x;   // float4 index < 49152
        ((float4*)xd)[zi] = (float4){0.f, 0.f, 0.f, 0.f};
        return;
    }
    int row = blk - 6656;
    const float4* xr = (const float4*)(x + (size_t)row * D_MODEL);
    float4 v = xr[threadIdx.x];
    float s  = v.x + v.y + v.z + v.w;
    float ss = v.x * v.x + v.y * v.y + v.z * v.z + v.w * v.w;
#pragma unroll
    for (int off = 32; off > 0; off >>= 1) {
        s  += __shfl_down(s,  off, 64);
        ss += __shfl_down(ss, off, 64);
    }
    __shared__ float sh_s[4], sh_ss[4];
    int wid = threadIdx.x >> 6;
    if ((threadIdx.x & 63) == 0) { sh_s[wid] = s; sh_ss[wid] = ss; }
    __syncthreads();
    float mu  = (sh_s[0] + sh_s[1] + sh_s[2] + sh_s[3]) * (1.0f / D_MODEL);
    float var = (sh_ss[0] + sh_ss[1] + sh_ss[2] + sh_ss[3]) * (1.0f / D_MODEL) - mu * mu;
    float rs = rsqrtf(var + 1e-5f);
    int c0 = threadIdx.x * 4;
    float vv[4] = {v.x, v.y, v.z, v.w};
#pragma unroll
    for (int j = 0; j < 4; j++) {
        int c = c0 + j;
        float o = (vv[j] - mu) * rs * g[c] + b[c];
        xn[(size_t)row * D_MODEL + c] = f2bf(o);
    }
}

// ============ LDS-staged B^T GEMM — 2-phase double-buffered pipeline ============
// MODE 0: bf16 store. MODE 4: f32 partial store to outF + z*M_ROWS*ldC.
template <int BM, int BN, int WM, int WN, int MODE>
__global__ __launch_bounds__(256) void gemm_lds(
    const __bf16* __restrict__ A, const __bf16* __restrict__ W,
    int K, int Ksteps, int ldC,
    float* __restrict__ outF, u16* __restrict__ outB) {
    constexpr int WCOLS = BN / (WN * 16);
    __shared__ __bf16 As[2][BM * 32];
    __shared__ __bf16 Bs[2][BN * 32];
    int tid  = threadIdx.x;
    int lane = tid & 63;
    int wid  = tid >> 6;
    int l16  = lane & 15;
    int quad = lane >> 4;
    int wr = wid / WCOLS;
    int wc = wid % WCOLS;
    int m0 = blockIdx.y * BM;
    int n0 = blockIdx.x * BN;
    int kbase = blockIdx.z * Ksteps * 32;

    f32x4 acc[WM][WN];
#pragma unroll
    for (int mi = 0; mi < WM; mi++)
#pragma unroll
        for (int nj = 0; nj < WN; nj++)
            acc[mi][nj] = (f32x4){0.f, 0.f, 0.f, 0.f};

    auto STAGE = [&](int buf, int ki) {
        int k0 = kbase + ki * 32;
#pragma unroll
        for (int i = 0; i < BM / 64; i++) {
            int t   = i * 256 + tid;
            int row = t >> 2;
            int cg  = (t & 3) ^ ((row >> 1) & 3);
            __builtin_amdgcn_global_load_lds(
                (const __attribute__((address_space(1))) u32*)(A + (size_t)(m0 + row) * K + k0 + cg * 8),
                (__attribute__((address_space(3))) u32*)(As[buf] + (i * 256 + wid * 64) * 8),
                16, 0, 0);
        }
#pragma unroll
        for (int i = 0; i < BN / 64; i++) {
            int t   = i * 256 + tid;
            int row = t >> 2;
            int cg  = (t & 3) ^ ((row >> 1) & 3);
            __builtin_amdgcn_global_load_lds(
                (const __attribute__((address_space(1))) u32*)(W + (size_t)(n0 + row) * K + k0 + cg * 8),
                (__attribute__((address_space(3))) u32*)(Bs[buf] + (i * 256 + wid * 64) * 8),
                16, 0, 0);
        }
    };

    STAGE(0, 0);
    __syncthreads();   // prologue: buf0 ready

    int cur = 0;
    for (int ki = 0; ki < Ksteps; ki++) {
        if (ki + 1 < Ksteps) STAGE(cur ^ 1, ki + 1);   // prefetch flies under compute

        bf16x8 af[WM], bfr[WN];
#pragma unroll
        for (int mi = 0; mi < WM; mi++) {
            int r  = wr * WM * 16 + mi * 16 + l16;
            int cg = quad ^ ((r >> 1) & 3);
            af[mi] = *(const bf16x8*)(As[cur] + r * 32 + cg * 8);
        }
#pragma unroll
        for (int nj = 0; nj < WN; nj++) {
            int r  = wc * WN * 16 + nj * 16 + l16;
            int cg = quad ^ ((r >> 1) & 3);
            bfr[nj] = *(const bf16x8*)(Bs[cur] + r * 32 + cg * 8);
        }
#pragma unroll
        for (int mi = 0; mi < WM; mi++)
#pragma unroll
            for (int nj = 0; nj < WN; nj++)
                acc[mi][nj] = __builtin_amdgcn_mfma_f32_16x16x32_bf16(
                    af[mi], bfr[nj], acc[mi][nj], 0, 0, 0);

        __syncthreads();   // drains prefetch (vmcnt0) + all waves done reading cur
        cur ^= 1;
    }

    float* outP = (MODE == 4) ? outF + (size_t)blockIdx.z * M_ROWS * ldC : outF;
#pragma unroll
    for (int mi = 0; mi < WM; mi++) {
#pragma unroll
        for (int nj = 0; nj < WN; nj++) {
            int col = n0 + wc * WN * 16 + nj * 16 + l16;
#pragma unroll
            for (int r = 0; r < 4; r++) {
                int row = m0 + wr * WM * 16 + mi * 16 + quad * 4 + r;
                float v = acc[mi][nj][r];
                if (MODE == 0) {
                    outB[(size_t)row * ldC + col] = f2bf(v);
                } else {
                    outP[(size_t)row * ldC + col] = v;
                }
            }
        }
    }
}

// ---------------- out_proj partial reduce (4 partials) + residual ----------------
__global__ __launch_bounds__(256) void out_reduce(
    const float* __restrict__ p, const float* __restrict__ x,
    float* __restrict__ out) {
    int idx = blockIdx.x * 256 + threadIdx.x;   // float4 index
    const int N = M_ROWS * D_MODEL;
    float4 a = ((const float4*)p)[idx];
    float4 b = ((const float4*)(p + N))[idx];
    float4 c = ((const float4*)(p + 2 * N))[idx];
    float4 d = ((const float4*)(p + 3 * N))[idx];
    float4 r = ((const float4*)x)[idx];
    float4 o;
    o.x = a.x + b.x + c.x + d.x + r.x;
    o.y = a.y + b.y + c.y + d.y + r.y;
    o.z = a.z + b.z + c.z + d.z + r.z;
    o.w = a.w + b.w + c.w + d.w + r.w;
    ((float4*)out)[idx] = o;
}

// ---------------- x_proj GEMM: K-split partials accumulated via f32 atomicAdd ----------------
// xd pre-zeroed in prep (0.75 MB, L2-resident). grid (2, 32, 8).
__global__ __launch_bounds__(256) void gemm_xp(
    const __bf16* __restrict__ A, const __bf16* __restrict__ W,
    float* __restrict__ outF) {
    const int K = D_INNER, Ksplit = D_INNER / 8, Nw = 96;
    int lane = threadIdx.x & 63;
    int wid  = threadIdx.x >> 6;
    int m0 = blockIdx.y * 64;
    int n0 = blockIdx.x * 64;
    int kc = blockIdx.z;
    int l16  = lane & 15;
    int quad = lane >> 4;
    int mrow = m0 + wid * 16 + l16;

    const __bf16* ap = A + (size_t)mrow * K + kc * Ksplit + quad * 8;
    const __bf16* wp[4];
#pragma unroll
    for (int j = 0; j < 4; j++) {
        int nc = n0 + j * 16 + l16;
        if (nc > Nw - 1) nc = Nw - 1;
        wp[j] = W + (size_t)nc * K + kc * Ksplit + quad * 8;
    }
    f32x4 acc[4];
#pragma unroll
    for (int j = 0; j < 4; j++) acc[j] = (f32x4){0.f, 0.f, 0.f, 0.f};

    for (int k = 0; k < Ksplit; k += 32) {
        bf16x8 a = *(const bf16x8*)ap;
        ap += 32;
#pragma unroll
        for (int j = 0; j < 4; j++) {
            bf16x8 bfr = *(const bf16x8*)wp[j];
            wp[j] += 32;
            acc[j] = __builtin_amdgcn_mfma_f32_16x16x32_bf16(a, bfr, acc[j], 0, 0, 0);
        }
    }
#pragma unroll
    for (int j = 0; j < 4; j++) {
        int col = n0 + j * 16 + l16;
        if (col < Nw) {
#pragma unroll
            for (int r = 0; r < 4; r++) {
                int row = m0 + wid * 16 + quad * 4 + r;
                atomicAdd(outF + (size_t)row * 96 + col, acc[j][r]);
            }
        }
    }
}

// ---------------- causal depthwise conv + SiLU — LDS-tiled (R12 win) ----------------
#define XSLOTS 9   // row stride = 9 x 16B = 144B (16B-aligned rows, bank-spread)
__global__ __launch_bounds__(256) void conv_tile(
    const u16* __restrict__ xz, const float* __restrict__ cw,
    const float* __restrict__ cb, u16* __restrict__ uc) {
    __shared__ u16 Xs[35 * XSLOTS * 8];   // 5.04 KB (u16x8 slots)
    __shared__ float CW[4][64];           // 1 KB
    __shared__ float CB[64];              // 256 B
    int tid = threadIdx.x;
    int mt = blockIdx.x, b = blockIdx.z;
    int d0 = blockIdx.y * 64;
    int mbase = b * SEQ_L + mt * CHUNK;

    // stage xz u-half rows mbase-3 .. mbase+31 (35 rows x 8 x u16x8)
    for (int i = tid; i < 35 * 8; i += 256) {
        int s = i >> 3, slot = i & 7;
        u16x8 v = {0, 0, 0, 0, 0, 0, 0, 0};
        if (mt > 0 || s >= 3) {
            int m = mbase - 3 + s;
            v = *(const u16x8*)(xz + (size_t)m * (2 * D_INNER) + d0 + slot * 8);
        }
        *(u16x8*)(Xs + (s * XSLOTS + (slot ^ (s & 7))) * 8) = v;
    }
    if (tid < 64) {
        CB[tid] = cb[d0 + tid];
        float4 w = *(const float4*)(cw + (size_t)(d0 + tid) * 4);
        CW[0][tid] = w.x; CW[1][tid] = w.y; CW[2][tid] = w.z; CW[3][tid] = w.w;
    }
    __syncthreads();

    int r = tid >> 3;            // output row 0..31
    int slot = tid & 7;          // d-group
    int dbase = slot * 8;
    float s[8];
    {
        float4 b0 = *(const float4*)&CB[dbase];
        float4 b1 = *(const float4*)&CB[dbase + 4];
        s[0] = b0.x; s[1] = b0.y; s[2] = b0.z; s[3] = b0.w;
        s[4] = b1.x; s[5] = b1.y; s[6] = b1.z; s[7] = b1.w;
    }
#pragma unroll
    for (int j = 0; j < 4; j++) {
        int sr = r + j;          // staged row for tap j (global m = mbase + r - 3 + j)
        u16x8 xv = *(const u16x8*)(Xs + (sr * XSLOTS + (slot ^ (sr & 7))) * 8);
        float4 w0 = *(const float4*)&CW[j][dbase];
        float4 w1 = *(const float4*)&CW[j][dbase + 4];
        float wv[8] = {w0.x, w0.y, w0.z, w0.w, w1.x, w1.y, w1.z, w1.w};
#pragma unroll
        for (int q = 0; q < 8; q++) {
            s[q] += wv[q] * bf2f(xv[q]);
        }
    }
    u16x8 o;
#pragma unroll
    for (int q = 0; q < 8; q++) {
        float sig = 1.f / (1.f + __expf(-s[q]));
        o[q] = f2bf(s[q] * sig);
    }
    *(u16x8*)(uc + (size_t)(mbase + r) * D_INNER + d0 + dbase) = o;
}

// ================= scan_chunk with FUSED delta GEMM =================
// grid (NCHUNK=32, D_INNER/64, NBATCH) = 2048 blocks (8/CU).
// Each block computes its own 32x64 dl patch (M=32,N=64,K=64 MFMA from xd dt-cols +
// L2-resident w_dt; identical acc order/softplus/f2bf to the old gemm_dt ->
// bit-identical dl), writes it to LDS for the scan AND to global for scan_apply.
__global__ __launch_bounds__(256) void scan_chunk(
    const u16* __restrict__ uc, const float* __restrict__ xd,
    const __bf16* __restrict__ w_dt, const float* __restrict__ dt_b,
    const float* __restrict__ A_log,
    float* __restrict__ Pst, float* __restrict__ Sst,
    u16* __restrict__ dl_out) {
    __shared__ float Bsh[CHUNK][16];   // 2 KB
    __shared__ u16 DLs[CHUNK][64];     // 4 KB (computed in-block)
    __shared__ u16 UCs[CHUNK][64];     // 4 KB
    int tid  = threadIdx.x;
    int lane = tid & 63;
    int w    = tid >> 6;
    int dsub = lane & 15;
    int g    = lane >> 4;
    int n0   = g * 4;
    int l16  = lane & 15;
    int quad = lane >> 4;
    int c = blockIdx.x, b = blockIdx.z;
    int d0 = blockIdx.y * 64;
    int dloc = w * 16 + dsub;
    int d = d0 + dloc;
    int mbase = b * SEQ_L + c * CHUNK;

    {   // coalesced staging of uc tile (dl is computed, not loaded)
        int r = tid >> 3, c8 = (tid & 7) * 8;
        *(u16x8*)&UCs[r][c8] = *(const u16x8*)(uc + (size_t)(mbase + r) * D_INNER + d0 + c8);
    }
    if (tid < CHUNK * 4) {   // stage B rows: 32 x 16 floats
        int row = tid >> 2, q = tid & 3;
        *(float4*)&Bsh[row][q * 4] =
            *(const float4*)(xd + (size_t)(mbase + row) * 96 + DT_RANK + q * 4);
    }

    // ---- fused delta GEMM: wave w owns dl cols d0 + w*16 + l16 ----
    int dcol = d0 + w * 16 + l16;
    f32x4 acc2[2];
    acc2[0] = (f32x4){0.f, 0.f, 0.f, 0.f};
    acc2[1] = (f32x4){0.f, 0.f, 0.f, 0.f};
#pragma unroll
    for (int kk = 0; kk < 2; kk++) {
        bf16x8 bfr = *(const bf16x8*)(w_dt + (size_t)dcol * DT_RANK + kk * 32 + quad * 8);
#pragma unroll
        for (int mi = 0; mi < 2; mi++) {
            const float* ap = xd + (size_t)(mbase + mi * 16 + l16) * 96 + kk * 32 + quad * 8;
            float4 v0 = *(const float4*)(ap);
            float4 v1 = *(const float4*)(ap + 4);
            u16x8 pk;
            pk[0] = f2bf(v0.x); pk[1] = f2bf(v0.y); pk[2] = f2bf(v0.z); pk[3] = f2bf(v0.w);
            pk[4] = f2bf(v1.x); pk[5] = f2bf(v1.y); pk[6] = f2bf(v1.z); pk[7] = f2bf(v1.w);
            bf16x8 a = __builtin_bit_cast(bf16x8, pk);
            acc2[mi] = __builtin_amdgcn_mfma_f32_16x16x32_bf16(a, bfr, acc2[mi], 0, 0, 0);
        }
    }
    {
        float bias_v = dt_b[dcol];
#pragma unroll
        for (int mi = 0; mi < 2; mi++)
#pragma unroll
            for (int r = 0; r < 4; r++) {
                int t = mi * 16 + quad * 4 + r;
                float tv = acc2[mi][r] + bias_v;
                float sp = (tv > 20.f) ? tv : log1pf(__expf(tv));
                DLs[t][w * 16 + l16] = f2bf(sp);
            }
    }
    __syncthreads();

    {   // coalesced copy-out: dl patch -> global for scan_apply
        int r = tid >> 3, c8 = (tid & 7) * 8;
        *(u16x8*)(dl_out + (size_t)(mbase + r) * D_INNER + d0 + c8) = *(u16x8*)&DLs[r][c8];
    }

    float a[4];
    {
        float4 a0 = *(const float4*)(A_log + d * D_STATE + n0);
        a[0] = -__expf(a0.x); a[1] = -__expf(a0.y);
        a[2] = -__expf(a0.z); a[3] = -__expf(a0.w);
    }
    float P[4] = {1.f, 1.f, 1.f, 1.f}, S[4] = {0.f, 0.f, 0.f, 0.f};

    for (int t0 = 0; t0 < CHUNK; t0 += 4) {
        float dlv[4], uv[4];
#pragma unroll
        for (int i = 0; i < 4; i++) {
            dlv[i] = bf2f(DLs[t0 + i][dloc]);
            uv[i]  = bf2f(UCs[t0 + i][dloc]);
        }
#pragma unroll
        for (int i = 0; i < 4; i++) {
            float c1 = dlv[i] * uv[i];
#pragma unroll
            for (int j = 0; j < 4; j++) {
                float dA = __expf(dlv[i] * a[j]);
                P[j] *= dA;
                S[j] = dA * S[j] + c1 * Bsh[t0 + i][n0 + j];
            }
        }
    }
    size_t s = ((size_t)(b * D_INNER + d) * NCHUNK + c) * D_STATE + n0;
    *(float4*)(Pst + s) = (float4){P[0], P[1], P[2], P[3]};
    *(float4*)(Sst + s) = (float4){S[0], S[1], S[2], S[3]};
}

__global__ __launch_bounds__(256) void scan_combine(
    const float* __restrict__ Pst, const float* __restrict__ Sst,
    float* __restrict__ Hin) {
    int idx = blockIdx.x * 256 + threadIdx.x;   // < NBATCH*D_INNER*D_STATE
    int bd = idx >> 4;
    int n  = idx & 15;
    float h = 0.f;
#pragma unroll
    for (int c = 0; c < NCHUNK; ++c) {
        size_t s = ((size_t)bd * NCHUNK + c) * D_STATE + n;
        Hin[s] = h;
        h = Pst[s] * h + Sst[s];
    }
}

__global__ __launch_bounds__(256) void scan_apply(
    const u16* __restrict__ delta, const u16* __restrict__ uc,
    const float* __restrict__ xd, const u16* __restrict__ xz,
    const float* __restrict__ A_log, const float* __restrict__ Dsk,
    const float* __restrict__ Hin, u16* __restrict__ yg) {
    __shared__ float BCs[CHUNK][32];   // 4 KB
    __shared__ u16 DLs[CHUNK][64];     // 4 KB
    __shared__ u16 UCs[CHUNK][64];     // 4 KB
    __shared__ u16 Zs[CHUNK][64];      // 4 KB
    int tid  = threadIdx.x;
    int lane = tid & 63;
    int w    = tid >> 6;
    int dsub = lane & 15;
    int g    = lane >> 4;
    int n0   = g * 4;
    int c = blockIdx.x, b = blockIdx.z;
    int d0 = blockIdx.y * 64;
    int dloc = w * 16 + dsub;
    int d = d0 + dloc;
    int mbase = b * SEQ_L + c * CHUNK;

    {   // coalesced staging of dl/uc/z tiles
        int r = tid >> 3, c8 = (tid & 7) * 8;
        size_t gb = (size_t)(mbase + r) * D_INNER + d0 + c8;
        *(u16x8*)&DLs[r][c8] = *(const u16x8*)(delta + gb);
        *(u16x8*)&UCs[r][c8] = *(const u16x8*)(uc + gb);
        *(u16x8*)&Zs[r][c8]  = *(const u16x8*)(
            xz + (size_t)(mbase + r) * (2 * D_INNER) + D_INNER + d0 + c8);
    }
    {   // stage B+C rows: 32 x 32 floats = 256 float4s
        int row = tid >> 3, q = tid & 7;
        *(float4*)&BCs[row][q * 4] =
            *(const float4*)(xd + (size_t)(mbase + row) * 96 + DT_RANK + q * 4);
    }
    __syncthreads();

    float a[4];
    {
        float4 a0 = *(const float4*)(A_log + d * D_STATE + n0);
        a[0] = -__expf(a0.x); a[1] = -__expf(a0.y);
        a[2] = -__expf(a0.z); a[3] = -__expf(a0.w);
    }
    float h[4];
    {
        float4 h0 = *(const float4*)(Hin +
            (((size_t)(b * D_INNER + d) * NCHUNK + c) * D_STATE + n0));
        h[0] = h0.x; h[1] = h0.y; h[2] = h0.z; h[3] = h0.w;
    }
    float dsk = Dsk[d];

    for (int t0 = 0; t0 < CHUNK; t0 += 4) {
        float dlv[4], uv[4], zv[4];
#pragma unroll
        for (int i = 0; i < 4; i++) {
            dlv[i] = bf2f(DLs[t0 + i][dloc]);
            uv[i]  = bf2f(UCs[t0 + i][dloc]);
            zv[i]  = bf2f(Zs[t0 + i][dloc]);
        }
#pragma unroll
        for (int i = 0; i < 4; i++) {
            int t = t0 + i;
            float c1 = dlv[i] * uv[i];
            float y = 0.f;
#pragma unroll
            for (int j = 0; j < 4; j++) {
                float dA = __expf(dlv[i] * a[j]);
                h[j] = dA * h[j] + c1 * BCs[t][n0 + j];
                y += h[j] * BCs[t][16 + n0 + j];
            }
            y += __shfl_xor(y, 16);
            y += __shfl_xor(y, 32);
            if (g == 0) {
                float z = zv[i];
                float yv = y + uv[i] * dsk;
                float gt = z / (1.f + __expf(-z));
                yg[(size_t)(mbase + t) * D_INNER + d] = f2bf(yv * gt);
            }
        }
    }
}

extern "C" void kernel_launch(void* const* d_in, const int* in_sizes, int n_in,
                              void* d_out, int out_size, void* d_ws, size_t ws_size,
                              hipStream_t stream) {
    const float* x         = (const float*)d_in[0];
    const float* ln_g      = (const float*)d_in[1];
    const float* ln_b      = (const float*)d_in[2];
    const float* in_proj_w = (const float*)d_in[3];
    const float* conv_w    = (const float*)d_in[4];
    const float* conv_b    = (const float*)d_in[5];
    const float* x_proj_w  = (const float*)d_in[6];
    const float* dt_proj_w = (const float*)d_in[7];
    const float* dt_proj_b = (const float*)d_in[8];
    const float* A_log     = (const float*)d_in[9];
    const float* Dsk       = (const float*)d_in[10];
    const float* out_proj_w= (const float*)d_in[11];

    // ws is 256 MiB. Every buffer gets its own region — no overlays.
    char* ws = (char*)d_ws;
    u16* xn   = (u16*)ws;    ws += (size_t)M_ROWS * D_MODEL * 2;        // 4 MB
    u16* xz   = (u16*)ws;    ws += (size_t)M_ROWS * 2 * D_INNER * 2;    // 16 MB
    u16* ucv  = (u16*)ws;    ws += (size_t)M_ROWS * D_INNER * 2;        // 8 MB
    float* xd = (float*)ws;  ws += (size_t)M_ROWS * 96 * 4;             // 0.75 MB
    u16* dl   = (u16*)ws;    ws += (size_t)M_ROWS * D_INNER * 2;        // 8 MB (bf16)
    u16* yg   = (u16*)ws;    ws += (size_t)M_ROWS * D_INNER * 2;        // 8 MB
    u16* w_in = (u16*)ws;    ws += (size_t)4194304 * 2;                 // 8 MB
    u16* w_out= (u16*)ws;    ws += (size_t)2097152 * 2;                 // 4 MB
    u16* w_xp = (u16*)ws;    ws += (size_t)196608 * 2;                  // 0.375 MB
    u16* w_dt = (u16*)ws;    ws += (size_t)131072 * 2;                  // 0.25 MB
    float* Pst = (float*)ws; ws += (size_t)NBATCH * D_INNER * D_STATE * NCHUNK * 4; // 8 MB
    float* Sst = (float*)ws; ws += (size_t)NBATCH * D_INNER * D_STATE * NCHUNK * 4; // 8 MB
    float* Hin = (float*)ws; ws += (size_t)NBATCH * D_INNER * D_STATE * NCHUNK * 4; // 8 MB
    float* opart = (float*)ws;                                          // 32 MB

    // 0. float4 weight casts + xd zero + LayerNorm — one dispatch
    prep<<<6656 + M_ROWS, 256, 0, stream>>>(
        in_proj_w, out_proj_w, x_proj_w, dt_proj_w, w_in, w_out, w_xp, w_dt,
        x, ln_g, ln_b, xn, xd);
    // 1. xz = xn @ in_proj_w^T — 2-phase pipelined 64x128 tile, 1024 blocks (4/CU)
    gemm_lds<64, 128, 4, 2, 0><<<dim3(4096 / 128, M_ROWS / 64, 1), 256, 0, stream>>>(
        (const __bf16*)xn, (const __bf16*)w_in, D_MODEL, D_MODEL / 32, 2 * D_INNER,
        nullptr, xz);
    // 2. causal depthwise conv + SiLU — LDS-tiled, 2048 blocks (8/CU)
    conv_tile<<<dim3(SEQ_L / CHUNK, D_INNER / 64, NBATCH), 256, 0, stream>>>(
        xz, conv_w, conv_b, ucv);
    // 3. x_dbl = u @ x_proj_w^T  (N=96), K-split x8 via f32 atomics into L2-resident xd
    gemm_xp<<<dim3(2, 32, 8), 256, 0, stream>>>(
        (const __bf16*)ucv, (const __bf16*)w_xp, xd);
    // 4+5a. scan_chunk with fused delta GEMM (replaces gemm_dt + old scan_chunk)
    dim3 sgrid(NCHUNK, D_INNER / 64, NBATCH);
    scan_chunk<<<sgrid, 256, 0, stream>>>(
        ucv, xd, (const __bf16*)w_dt, dt_proj_b, A_log, Pst, Sst, dl);
    // 5b/5c. combine + apply (unchanged)
    scan_combine<<<(NBATCH * D_INNER * D_STATE) / 256, 256, 0, stream>>>(Pst, Sst, Hin);
    scan_apply<<<sgrid, 256, 0, stream>>>(dl, ucv, xd, xz, A_log, Dsk, Hin, yg);
    // 6. out_proj partials — 2-phase pipelined (K=2048 split x4, 512 blocks 2/CU) + reduce
    gemm_lds<64, 128, 4, 2, 4><<<dim3(1024 / 128, M_ROWS / 64, 4), 256, 0, stream>>>(
        (const __bf16*)yg, (const __bf16*)w_out, D_INNER, D_INNER / 4 / 32, D_MODEL,
        opart, nullptr);
    out_reduce<<<(M_ROWS * D_MODEL / 4) / 256, 256, 0, stream>>>(
        opart, x, (float*)d_out);
}